// Round 6
// baseline (633.081 us; speedup 1.0000x reference)
//
#include <hip/hip_runtime.h>

typedef unsigned short u16;
typedef unsigned int u32;
typedef __attribute__((ext_vector_type(8))) short bf16x8;
typedef __attribute__((ext_vector_type(8))) _Float16 f16x8;
typedef __attribute__((ext_vector_type(4))) float f32x4;

__device__ __forceinline__ float b2f(u16 u) {
  union { u32 i; float f; } v; v.i = ((u32)u) << 16; return v.f;
}
__device__ __forceinline__ u16 f2b(float f) {
  u32 u = __builtin_bit_cast(u32, f);
  u32 r = u + 0x7FFFu + ((u >> 16) & 1u);
  return (u16)(r >> 16);
}
__device__ __forceinline__ u16 f2h(float f) {
  return __builtin_bit_cast(u16, (_Float16)f);
}
__device__ __forceinline__ float h2f(u16 u) {
  return (float)__builtin_bit_cast(_Float16, u);
}
__device__ __forceinline__ float wsum(float v) {
  #pragma unroll
  for (int o = 32; o; o >>= 1) v += __shfl_xor(v, o);
  return v;
}

// ---------- dtype detector: flag=0 bf16 storage, flag=1 fp32 ----------
__global__ void k_detect(const u32* x, int* flag) {
  int lane = threadIdx.x;
  u32 w = x[lane * 131 + 7];
  float v = b2f((u16)(w & 0xFFFF));
  float a = fabsf(v);
  bool sane = (a > 1e-3f) && (a < 100.0f);
  unsigned long long m = __ballot(sane);
  if (lane == 0) flag[0] = (__popcll(m) >= 32) ? 0 : 1;
}

// ---------- weight transposes + vec convert + sincos tables + nmax, ONE launch ----------
// ids 0..415: transposes; 416: vec convert; 417..1184: qtab/ktab sincos; 1185: nmaxg.
struct WtArgs {
  const void* s[8];
  const void* vq; const void* vk; const void* vs;
};
__global__ __launch_bounds__(256)
void k_wtab(WtArgs a, u16* wb, const int* flag, const int* spos, const int* tok,
            float2* qtab, float2* ktab, int* nmaxg) {
  __shared__ u16 Ts[64][66];
  int id = blockIdx.x, t = threadIdx.x;
  if (id >= 417) {
    if (id == 1185) {  // nmaxg[tile]: count of spos[n] < tok0 + tile*8 + 7 (QBLK=8)
      int lim = tok[0] + t * 8 + 7;
      int lo = 0, hi = 1024;
      #pragma unroll 1
      while (lo < hi) { int mid = (lo + hi) >> 1; if (spos[mid] < lim) lo = mid + 1; else hi = mid; }
      nmaxg[t] = lo;
      return;
    }
    int rid = (id - 417) * 4 + (t >> 6);
    int lane = t & 63;
    float invf = __expf(-(float)lane * (9.210340371976184f / 64.0f));
    if (rid < 2048) {
      float pos = (float)(tok[0] + rid);
      float sn, cs; sincosf(pos * invf, &sn, &cs);
      qtab[rid * 64 + lane] = make_float2(cs, sn);
    } else {
      int n = rid - 2048;
      float pos = (float)spos[n];
      float sn, cs; sincosf(pos * invf, &sn, &cs);
      ktab[n * 64 + lane] = make_float2(cs, sn);
    }
    return;
  }
  int dt = flag[0];
  if (id == 416) {  // vec convert
    u16* dq = wb + 1703936; u16* dk = wb + 1704064; u16* ds = wb + 1704192;
    if (t < 128) dq[t] = dt ? f2b(((const float*)a.vq)[t]) : ((const u16*)a.vq)[t];
    else if (t < 256) dk[t-128] = dt ? f2b(((const float*)a.vk)[t-128]) : ((const u16*)a.vk)[t-128];
    if (t < 16) ds[t] = dt ? f2b(((const float*)a.vs)[t]) : ((const u16*)a.vs)[t];
    return;
  }
  const int cum[9] = {0,64,128,144,160,224,288,352,416};
  const int gsh[8] = {1,1,1,1,5,5,1,5};
  const int Ks[8]  = {2048,2048,512,512,128,128,2048,128};
  const int Ns[8]  = {128,128,128,128,2048,2048,128,2048};
  const unsigned dsts[8] = {0,262144,524288,589824,655360,917504,1179648,1441792};
  int seg = 0;
  #pragma unroll
  for (int i = 0; i < 7; ++i) seg += (id >= cum[i+1]);
  int rel = id - cum[seg];
  int bx = rel & ((1 << gsh[seg]) - 1), by = rel >> gsh[seg];
  int K = Ks[seg], N = Ns[seg];
  const void* src = a.s[seg];
  u16* dst = wb + dsts[seg];
  int col0 = bx * 64, k0 = by * 64;
  int lr = t >> 4, lc = (t & 15) * 4;
  if (dt) {
    #pragma unroll
    for (int p = 0; p < 4; ++p) {
      int kr = lr + p * 16;
      float4 v = *(const float4*)((const float*)src + (size_t)(k0 + kr) * N + col0 + lc);
      Ts[kr][lc+0] = f2b(v.x); Ts[kr][lc+1] = f2b(v.y);
      Ts[kr][lc+2] = f2b(v.z); Ts[kr][lc+3] = f2b(v.w);
    }
  } else {
    #pragma unroll
    for (int p = 0; p < 4; ++p) {
      int kr = lr + p * 16;
      uint2 v = *(const uint2*)((const u16*)src + (size_t)(k0 + kr) * N + col0 + lc);
      *(uint2*)&Ts[kr][lc] = v;
    }
  }
  __syncthreads();
  int col = t >> 2, ks = (t & 3) * 16;
  u16 tmp[16];
  #pragma unroll
  for (int i = 0; i < 16; ++i) tmp[i] = Ts[ks + i][col];
  u16* dp = dst + (size_t)(col0 + col) * K + k0 + ks;
  *(uint4*)dp = *(uint4*)&tmp[0];
  *(uint4*)(dp + 8) = *(uint4*)&tmp[8];
}

// ---------- skinny GEMM body: C = A[M][K]*B, BT[N][K]; M-tile 16, N=JW*64 ----------
template<int JW>
__device__ __forceinline__ void skinny_body(const void* A, const u16* BT, u16* C0, u16* C1,
    int K, bool a32, int m0, int tid, u16 (*As)[40]) {
  int wave = tid >> 6, lane = tid & 63, quad = lane >> 4, l16 = lane & 15;
  f32x4 acc[JW];
  #pragma unroll
  for (int j = 0; j < JW; ++j) acc[j] = (f32x4){0.f,0.f,0.f,0.f};
  int row32 = tid >> 4, kp32 = (tid & 15) * 2;
  int row16 = tid >> 2, kp16 = (tid & 3) * 8;
  float2 pf32 = {};
  uint4 pf16 = {};
  if (a32) pf32 = *(const float2*)((const float*)A + (size_t)(m0+row32)*K + kp32);
  else if (tid < 64) pf16 = *(const uint4*)((const u16*)A + (size_t)(m0+row16)*K + kp16);
  uint4 bf[JW];
  #pragma unroll
  for (int j = 0; j < JW; ++j) {
    int col = wave*(JW*16) + j*16 + l16;
    bf[j] = *(const uint4*)(BT + (size_t)col*K + quad*8);
  }
  for (int k0 = 0; k0 < K; k0 += 32) {
    if (a32) { As[row32][kp32] = f2b(pf32.x); As[row32][kp32+1] = f2b(pf32.y); }
    else if (tid < 64) *(uint4*)&As[row16][kp16] = pf16;
    __syncthreads();
    int k1 = k0 + 32;
    uint4 bn[JW];
    if (k1 < K) {
      if (a32) pf32 = *(const float2*)((const float*)A + (size_t)(m0+row32)*K + k1 + kp32);
      else if (tid < 64) pf16 = *(const uint4*)((const u16*)A + (size_t)(m0+row16)*K + k1 + kp16);
      #pragma unroll
      for (int j = 0; j < JW; ++j) {
        int col = wave*(JW*16) + j*16 + l16;
        bn[j] = *(const uint4*)(BT + (size_t)col*K + k1 + quad*8);
      }
    }
    bf16x8 af = *(const bf16x8*)&As[l16][quad*8];
    #pragma unroll
    for (int j = 0; j < JW; ++j)
      acc[j] = __builtin_amdgcn_mfma_f32_16x16x32_bf16(af, __builtin_bit_cast(bf16x8, bf[j]), acc[j], 0, 0, 0);
    __syncthreads();
    #pragma unroll
    for (int j = 0; j < JW; ++j) bf[j] = bn[j];
  }
  #pragma unroll
  for (int j = 0; j < JW; ++j) {
    int col = wave*(JW*16) + j*16 + l16;
    u16* Cp = (col < 128) ? C0 : C1;
    int cc = col & 127;
    #pragma unroll
    for (int r = 0; r < 4; ++r)
      Cp[(size_t)(m0 + quad*4 + r)*128 + cc] = f2b(acc[j][r]);
  }
}

// ---------- up GEMM body: C[M][N] = A[M][128]*B, BT[N][128]; 64x64 tile ----------
__device__ __forceinline__ void gemm_up_body(const u16* A, const u16* BT, void* C, int ldc,
    bool o32, int m0, int n0, int tid, u16 (*As)[40]) {
  int wave = tid >> 6, lane = tid & 63, quad = lane >> 4, l16 = lane & 15;
  f32x4 acc[4] = {};
  int row = tid >> 2, kp = (tid & 3) * 8;
  uint4 pa = *(const uint4*)(A + (size_t)(m0+row)*128 + kp);
  uint4 bf[4];
  #pragma unroll
  for (int j = 0; j < 4; ++j)
    bf[j] = *(const uint4*)(BT + (size_t)(n0 + j*16 + l16)*128 + quad*8);
  #pragma unroll
  for (int k0 = 0; k0 < 128; k0 += 32) {
    *(uint4*)&As[row][kp] = pa;
    __syncthreads();
    uint4 bn[4];
    if (k0 < 96) {
      pa = *(const uint4*)(A + (size_t)(m0+row)*128 + k0 + 32 + kp);
      #pragma unroll
      for (int j = 0; j < 4; ++j)
        bn[j] = *(const uint4*)(BT + (size_t)(n0 + j*16 + l16)*128 + k0 + 32 + quad*8);
    }
    bf16x8 af = *(const bf16x8*)&As[wave*16 + l16][quad*8];
    #pragma unroll
    for (int j = 0; j < 4; ++j)
      acc[j] = __builtin_amdgcn_mfma_f32_16x16x32_bf16(af, __builtin_bit_cast(bf16x8, bf[j]), acc[j], 0, 0, 0);
    __syncthreads();
    #pragma unroll
    for (int j = 0; j < 4; ++j) bf[j] = bn[j];
  }
  #pragma unroll
  for (int j = 0; j < 4; ++j) {
    #pragma unroll
    for (int r = 0; r < 4; ++r) {
      size_t ci = (size_t)(m0 + wave*16 + quad*4 + r)*ldc + n0 + j*16 + l16;
      float v = acc[j][r];
      if (o32) ((float*)C)[ci] = v; else ((u16*)C)[ci] = f2b(v);
    }
  }
}

// ---------- k post body: RMSNorm+RoPE (sincos from ktab); -> kT ----------
__device__ __forceinline__ void kpost_body(const u16* kraw, u16* kT, const u16* kw,
                                           const float2* ktab, int rel, int tid) {
  int wave = tid >> 6, lane = tid & 63;
  int rr = rel * 4 + wave;               // (b*1024+n)*16 + h
  int n = (rr >> 4) & 1023, b = rr >> 14, h = rr & 15;
  size_t base = (size_t)rr * 128;
  float x0 = b2f(kraw[base + lane]);
  float x1 = b2f(kraw[base + lane + 64]);
  float ss = wsum(x0*x0 + x1*x1);
  float inv = rsqrtf(ss * (1.0f/128.0f) + 1e-6f);
  float y0 = x0 * inv * b2f(kw[lane]);
  float y1 = x1 * inv * b2f(kw[lane + 64]);
  float2 cs2 = ktab[n * 64 + lane];
  size_t ob = ((size_t)(b*16 + h) * 1024 + n) * 128;
  kT[ob + lane]      = f2b(y0*cs2.x - y1*cs2.y);
  kT[ob + lane + 64] = f2b(y1*cs2.x + y0*cs2.y);
}

// ---------- V transpose body: vraw -> vtt[b,h,dh,n] (f16) ----------
__device__ __forceinline__ void vtrans_body(const u16* vraw, u16* vtt, int bid, int t,
                                            u16 (*Vs)[136]) {
  int ng = bid & 15, bh = bid >> 4;
  int b = bh >> 4, h = bh & 15;
  int n0 = ng * 64;
  int li = t >> 4, seg = (t & 15) * 8;
  #pragma unroll
  for (int p = 0; p < 4; ++p) {
    int i = li + p * 16;
    size_t row = (size_t)(b*1024 + n0 + i) * 16 + h;
    *(uint4*)&Vs[i][seg] = *(const uint4*)(vraw + row*128 + seg);
  }
  __syncthreads();
  int dh = t >> 1, nh = (t & 1) * 32;
  u16 outv[32];
  #pragma unroll
  for (int i = 0; i < 32; ++i) outv[i] = f2h(b2f(Vs[nh + i][dh]));
  u16* dst = vtt + ((size_t)bh * 128 + dh) * 1024 + n0 + nh;
  *(uint4*)(dst)      = *(uint4*)&outv[0];
  *(uint4*)(dst + 8)  = *(uint4*)&outv[8];
  *(uint4*)(dst + 16) = *(uint4*)&outv[16];
  *(uint4*)(dst + 24) = *(uint4*)&outv[24];
}

// ---------- merged launches ----------
__global__ __launch_bounds__(256)
void k_down_all(const void* x, const void* snap, const u16* BdT, const u16* BkvT,
                u16* qlat, u16* glat, u16* kraw, u16* vraw, const int* flag) {
  __shared__ u16 As[16][40];
  int id = blockIdx.x;
  bool a32 = flag[0] != 0;
  if (id < 256) skinny_body<4>(x, BdT, qlat, glat, 2048, a32, id*16, threadIdx.x, As);
  else          skinny_body<4>(snap, BkvT, kraw, vraw, 512, a32, (id-256)*16, threadIdx.x, As);
}

__global__ __launch_bounds__(256)
void k_mid_all(const u16* qlat, const u16* glat, const u16* WquT, const u16* WguT,
               u16* qraw, u16* graw, const u16* kraw, u16* kT, const u16* vraw, u16* vtt,
               const u16* ckw, const float2* ktab, const int* flag) {
  __shared__ u16 smem[64*136];
  int id = blockIdx.x, tid = threadIdx.x;
  if (id < 4096) {
    u16 (*As)[40] = (u16 (*)[40])smem;
    int rel = id & 2047;
    const u16* A  = (id < 2048) ? qlat : glat;
    const u16* BT = (id < 2048) ? WquT : WguT;
    u16* C        = (id < 2048) ? qraw : graw;
    gemm_up_body(A, BT, C, 2048, false, (rel >> 5) * 64, (rel & 31) * 64, tid, As);
  } else if (id < 12288) {
    kpost_body(kraw, kT, ckw, ktab, id - 4096, tid);
  } else {
    vtrans_body(vraw, vtt, id - 12288, tid, (u16 (*)[136])smem);
  }
}

// ---------- k_olat K-split: 1024 blocks (256 m-tiles x 4 K-slices) -> f32 partials ----------
__global__ __launch_bounds__(256)
void k_olat_part(const u16* Ao, const u16* BT, float* P) {
  __shared__ u16 As[16][40];
  int bid = blockIdx.x;
  int ks = bid & 3, m0 = (bid >> 2) * 16;
  int kbase = ks * 512;
  int tid = threadIdx.x;
  int wave = tid >> 6, lane = tid & 63, quad = lane >> 4, l16 = lane & 15;
  f32x4 acc[2] = {};
  int row16 = tid >> 2, kp16 = (tid & 3) * 8;
  uint4 pf16 = {};
  if (tid < 64) pf16 = *(const uint4*)(Ao + (size_t)(m0+row16)*2048 + kbase + kp16);
  uint4 bf[2];
  #pragma unroll
  for (int j = 0; j < 2; ++j) {
    int col = wave*32 + j*16 + l16;
    bf[j] = *(const uint4*)(BT + (size_t)col*2048 + kbase + quad*8);
  }
  for (int k0 = 0; k0 < 512; k0 += 32) {
    if (tid < 64) *(uint4*)&As[row16][kp16] = pf16;
    __syncthreads();
    int k1 = k0 + 32;
    uint4 bn[2];
    if (k1 < 512) {
      if (tid < 64) pf16 = *(const uint4*)(Ao + (size_t)(m0+row16)*2048 + kbase + k1 + kp16);
      #pragma unroll
      for (int j = 0; j < 2; ++j) {
        int col = wave*32 + j*16 + l16;
        bn[j] = *(const uint4*)(BT + (size_t)col*2048 + kbase + k1 + quad*8);
      }
    }
    bf16x8 afr = *(const bf16x8*)&As[l16][quad*8];
    #pragma unroll
    for (int j = 0; j < 2; ++j)
      acc[j] = __builtin_amdgcn_mfma_f32_16x16x32_bf16(afr, __builtin_bit_cast(bf16x8, bf[j]), acc[j], 0, 0, 0);
    __syncthreads();
    #pragma unroll
    for (int j = 0; j < 2; ++j) bf[j] = bn[j];
  }
  #pragma unroll
  for (int j = 0; j < 2; ++j) {
    int col = wave*32 + j*16 + l16;
    #pragma unroll
    for (int r = 0; r < 4; ++r)
      P[((size_t)ks*4096 + m0 + quad*4 + r)*128 + col] = acc[j][r];
  }
}

// ---------- k_osum: sum 4 f32 partial slabs -> olat bf16 ----------
__global__ __launch_bounds__(256)
void k_osum(const float* P, u16* olat) {
  int idx = (blockIdx.x * 256 + threadIdx.x) * 4;
  float4 a = *(const float4*)(P + idx);
  float4 b = *(const float4*)(P + 524288 + idx);
  float4 c = *(const float4*)(P + 1048576 + idx);
  float4 d = *(const float4*)(P + 1572864 + idx);
  u16 o4[4];
  o4[0] = f2b(((a.x + b.x) + c.x) + d.x);
  o4[1] = f2b(((a.y + b.y) + c.y) + d.y);
  o4[2] = f2b(((a.z + b.z) + c.z) + d.z);
  o4[3] = f2b(((a.w + b.w) + c.w) + d.w);
  *(uint2*)(olat + idx) = *(uint2*)&o4[0];
}

__global__ __launch_bounds__(256)
void k_gemm_up(const u16* A, const u16* BT, void* C, int ldc, const int* flag, int out_dyn) {
  __shared__ u16 As[64][40];
  gemm_up_body(A, BT, C, ldc, out_dyn && flag[0], blockIdx.y*64, blockIdx.x*64, threadIdx.x, As);
}

// ---------- attention phase 2 (v4/v6 numerics, QBLK=8): lockstep-2, one pass ----------
// NJ=16 only when nmax > 512, so cols 0..511 always < nmax -> no select on lower half.
template<int NJ>
__device__ __forceinline__ void attn_phase2(char* scB, float* rzb, int tl0, int lane,
                                            int nmax, float sinkv, bool do_search) {
  int c0 = lane * 8;
  float sv[2][NJ]; int key[2][NJ];
  #pragma unroll
  for (int s2 = 0; s2 < 2; ++s2) {
    int tl = tl0 + s2;
    int sxor = (tl & 7) << 4;
    const char* rowp = scB + tl*2048;
    uint4 r0 = *(const uint4*)(rowp + ((lane*16) ^ sxor));
    if constexpr (NJ == 16) {
      // nmax > 512 here: c0+j <= 511 < nmax always -> no select (v1-identical)
      #pragma unroll
      for (int j = 0; j < 8; ++j) sv[s2][j] = h2f(((const u16*)&r0)[j]);
      uint4 r1 = *(const uint4*)(rowp + (1024 + ((lane*16) ^ sxor)));
      #pragma unroll
      for (int j = 0; j < 8; ++j)
        sv[s2][j+8] = (c0 + j + 512 < nmax) ? h2f(((const u16*)&r1)[j]) : -INFINITY;
    } else {
      #pragma unroll
      for (int j = 0; j < 8; ++j)
        sv[s2][j] = (c0 + j < nmax) ? h2f(((const u16*)&r0)[j]) : -INFINITY;
    }
  }
  // local max + v1-exact key grid: key = (int)clamp(f*256+2048, 0, 4095)
  float mx[2];
  #pragma unroll
  for (int s2 = 0; s2 < 2; ++s2) {
    float m = -INFINITY;
    #pragma unroll
    for (int j = 0; j < NJ; ++j) {
      float f = sv[s2][j];
      m = fmaxf(m, f);
      float fs = fminf(fmaxf(f * 256.0f + 2048.0f, 0.0f), 4095.0f);
      key[s2][j] = (int)fs;
    }
    mx[s2] = m;
  }
  #pragma unroll
  for (int os = 32; os; os >>= 1) {
    mx[0] = fmaxf(mx[0], __shfl_xor(mx[0], os));
    mx[1] = fmaxf(mx[1], __shfl_xor(mx[1], os));
  }
  // 12-iter integer binary search, 2 rows lockstep (identical result to v1)
  int lo2[2] = {0, 0};
  if (do_search) {
    int hi2[2] = {4096, 4096};
    #pragma unroll 1
    for (int it = 0; it < 12; ++it) {
      #pragma unroll
      for (int s2 = 0; s2 < 2; ++s2) {
        int mid = (lo2[s2] + hi2[s2]) >> 1;
        int c = 0;
        #pragma unroll
        for (int j = 0; j < NJ; ++j) c += (int)__popcll(__ballot(key[s2][j] >= mid));
        if (c >= 64) lo2[s2] = mid; else hi2[s2] = mid;
      }
    }
  }
  // exp + interleaved sum butterfly; store UNSCALED f16 weights (v1-exact)
  float m2[2], zp[2];
  u16 wq[2][16];
  #pragma unroll
  for (int s2 = 0; s2 < 2; ++s2) {
    m2[s2] = fmaxf(mx[s2], sinkv);
    float z = 0.f;
    #pragma unroll
    for (int j = 0; j < NJ; ++j) {
      float e = (key[s2][j] >= lo2[s2] && sv[s2][j] > -1e37f) ? __expf(sv[s2][j] - m2[s2]) : 0.f;
      z += e;
      wq[s2][j] = f2h(e);
    }
    zp[s2] = z;
  }
  #pragma unroll
  for (int os = 32; os; os >>= 1) {
    zp[0] += __shfl_xor(zp[0], os);
    zp[1] += __shfl_xor(zp[1], os);
  }
  #pragma unroll
  for (int s2 = 0; s2 < 2; ++s2) {
    int tl = tl0 + s2;
    float Z = zp[s2] + __expf(sinkv - m2[s2]);
    if (lane == 0) rzb[tl] = 1.0f / Z;
    int sxor = (tl & 7) << 4;
    char* rowp = scB + tl*2048;
    *(uint4*)(rowp + ((lane*16) ^ sxor)) = *(uint4*)&wq[s2][0];
    if constexpr (NJ == 16)
      *(uint4*)(rowp + (1024 + ((lane*16) ^ sxor))) = *(uint4*)&wq[s2][8];
  }
}

// ---------- fused attention v7: QBLK=8, 8 blocks/CU ----------
// vs v6 (numerics bit-identical): 8 t-rows per block (8192 blocks), sc = 16 KB ->
// __launch_bounds__(256,8) = 32 waves/CU (max). MFMA fragments use row (l16&7);
// rows 8..15 of each 16-row MFMA are duplicates whose outputs are discarded by the
// quad<2 store guard. Phase-2 per wave: rows {2w, 2w+1}, single lockstep-2 pass.
// Cost accepted: phase-1/3 MFMA count doubles (MfmaUtil 4->~8%), K/V L2 reads double.
__global__ __launch_bounds__(256, 8)
void k_attn(const u16* qraw, const u16* kT, const u16* vtt, const u16* graw,
            const int* spos, const int* tok, const u16* sink, const u16* qw,
            const float2* qtab, const int* nmaxg, float* rzg, u16* o) {
  __shared__ u16 sc[8*1024];         // 16 KB: scores/weights (f16), swizzled rows
  char* scB = (char*)sc;
  u16 (*Qs)[136] = (u16 (*)[136])sc;  // transient overlay (consumed before sc writes)

  int tid = threadIdx.x;
  int wave = tid >> 6, lane = tid & 63, quad = lane >> 4, l16 = lane & 15;
  int bid0 = blockIdx.x;
  int bid = (bid0 & 7) * 1024 + (bid0 >> 3);  // XCD k -> contiguous chunk (4 bh slices)
  int tile = bid & 255, bh = bid >> 8;
  int h = bh & 15, b = bh >> 4;
  int t0 = tile * 8;
  int tok0 = tok[0];
  float* rzb = rzg + bid * 16;

  // fused q RMSNorm + RoPE into Qs rows 0..7 (wave w: rows 2w, 2w+1)
  {
    float qw0 = b2f(qw[lane]), qw1 = b2f(qw[lane + 64]);
    #pragma unroll 1
    for (int s = 0; s < 2; ++s) {
      int i = wave*2 + s;
      size_t base = ((size_t)(b*2048 + t0 + i))*2048 + h*128;
      float x0 = b2f(qraw[base + lane]);
      float x1 = b2f(qraw[base + lane + 64]);
      float ss = wsum(x0*x0 + x1*x1);
      float inv = rsqrtf(ss * (1.0f/128.0f) + 1e-6f);
      float y0 = x0 * inv * qw0;
      float y1 = x1 * inv * qw1;
      float2 cs2 = qtab[(size_t)(t0 + i)*64 + lane];
      Qs[i][lane]      = f2b(y0*cs2.x - y1*cs2.y);
      Qs[i][lane + 64] = f2b(y1*cs2.x + y0*cs2.y);
    }
  }
  __syncthreads();

  int nmax = nmaxg[tile];
  int pmax = (nmax + 63) >> 6;
  int kkmax = (nmax + 31) >> 5;

  bf16x8 af[4];
  #pragma unroll
  for (int ks = 0; ks < 4; ++ks) af[ks] = *(const bf16x8*)&Qs[l16 & 7][ks*32 + quad*8];
  __syncthreads();   // protect Qs before sc writes

  // phase 1: scores for p < pmax into swizzled sc (rows t<8; quad>=2 outputs discarded)
  const u16* kTb = kT + (size_t)bh * 131072;
  int nrow = wave*16 + l16;
  uint4 kf[4];
  int pn = 0;
  if (pmax > 0) {
    const u16* kr = kTb + (size_t)nrow * 128 + quad*8;
    #pragma unroll
    for (int ks = 0; ks < 4; ++ks) kf[ks] = *(const uint4*)(kr + ks*32);
    pn = spos[nrow];
  }
  int lim0 = tok0 + t0;
  #pragma unroll 1
  for (int p = 0; p < pmax; ++p) {
    uint4 kn[4];
    int pn_next = 0;
    if (p + 1 < pmax) {
      const u16* kr = kTb + (size_t)((p+1)*64 + nrow) * 128 + quad*8;
      #pragma unroll
      for (int ks = 0; ks < 4; ++ks) kn[ks] = *(const uint4*)(kr + ks*32);
      pn_next = spos[(p+1)*64 + nrow];
    }
    f32x4 c = {};
    __builtin_amdgcn_s_setprio(1);
    #pragma unroll
    for (int ks = 0; ks < 4; ++ks)
      c = __builtin_amdgcn_mfma_f32_16x16x32_bf16(af[ks], __builtin_bit_cast(bf16x8, kf[ks]), c, 0, 0, 0);
    __builtin_amdgcn_s_setprio(0);
    int n = p*64 + nrow;
    if (quad < 2) {
      #pragma unroll
      for (int r = 0; r < 4; ++r) {
        int t = quad*4 + r;             // 0..7
        float s = c[r] * 0.08838834764831845f;
        if (pn >= lim0 + t) s = -INFINITY;
        *(u16*)(scB + ((t*2048 + n*2) ^ ((t&7)<<4))) = f2h(s);
      }
    }
    #pragma unroll
    for (int ks = 0; ks < 4; ++ks) kf[ks] = kn[ks];
    pn = pn_next;
  }
  __syncthreads();

  float sinkv = b2f(sink[h]);

  // phase 2 (numerics == v1); rows {2w, 2w+1} per wave, single lockstep-2 pass
  int tl0 = wave*2;
  bool do_search = (nmax > 64);
  if (nmax > 512) attn_phase2<16>(scB, rzb, tl0, lane, nmax, sinkv, do_search);
  else            attn_phase2<8> (scB, rzb, tl0, lane, nmax, sinkv, do_search);
  __syncthreads();

  // prefetch rz + gate values for the epilogue (rows t<8 only)
  int dh0 = wave * 32;
  float rz4[4];
  u16 g0r[4], g1r[4];
  if (quad < 2) {
    #pragma unroll
    for (int r = 0; r < 4; ++r) {
      int t = quad*4 + r;
      rz4[r] = rzb[t];
      size_t oi = ((size_t)(b*2048 + t0 + t))*2048 + h*128 + dh0 + l16;
      g0r[r] = graw[oi];
      g1r[r] = graw[oi + 16];
    }
  }

  // phase 3: dense PV via MFMA f16 over kk < kkmax (A rows = sc rows l16&7)
  const u16* vbase = vtt + (size_t)bh * 131072;
  const u16* vr0 = vbase + (size_t)(dh0 + l16)*1024 + quad*8;
  const u16* vr1 = vbase + (size_t)(dh0 + 16 + l16)*1024 + quad*8;
  f32x4 acc0 = {}, acc1 = {};
  uint4 vf0 = *(const uint4*)vr0;
  uint4 vf1 = *(const uint4*)vr1;
  int axor = (l16 & 7) << 4;
  const char* arow = scB + (l16 & 7)*2048;
  #pragma unroll 1
  for (int kk = 0; kk < kkmax; ++kk) {
    uint4 vn0, vn1;
    if (kk + 1 < kkmax) {
      vn0 = *(const uint4*)(vr0 + (kk+1)*32);
      vn1 = *(const uint4*)(vr1 + (kk+1)*32);
    }
    f16x8 a = *(const f16x8*)(arow + ((kk*64 + quad*16) ^ axor));
    __builtin_amdgcn_s_setprio(1);
    acc0 = __builtin_amdgcn_mfma_f32_16x16x32_f16(a, __builtin_bit_cast(f16x8, vf0), acc0, 0, 0, 0);
    acc1 = __builtin_amdgcn_mfma_f32_16x16x32_f16(a, __builtin_bit_cast(f16x8, vf1), acc1, 0, 0, 0);
    __builtin_amdgcn_s_setprio(0);
    vf0 = vn0; vf1 = vn1;
  }

  // epilogue (rows t<8): *1/Z, *sigmoid(gate), store (o aliases graw; same-thread RaW)
  if (quad < 2) {
    #pragma unroll
    for (int r = 0; r < 4; ++r) {
      int t = quad*4 + r;
      size_t oi = ((size_t)(b*2048 + t0 + t))*2048 + h*128 + dh0 + l16;
      float g0 = 1.0f / (1.0f + __expf(-b2f(g0r[r])));
      float g1 = 1.0f / (1.0f + __expf(-b2f(g1r[r])));
      o[oi] = f2b(acc0[r] * rz4[r] * g0);
      o[oi + 16] = f2b(acc1[r] * rz4[r] * g1);
    }
  }
}

extern "C" void kernel_launch(void* const* d_in, const int* in_sizes, int n_in,
                              void* d_out, int out_size, void* d_ws, size_t ws_size,
                              hipStream_t stream) {
  char* ws = (char*)d_ws;
  int* flag = (int*)(ws + 0);
  u16* wb = (u16*)(ws + 4096);

  // wb element offsets
  u16* BdT  = wb + 0;        // [256][2048]
  u16* BkvT = wb + 524288;   // [256][512]
  u16* WquT = wb + 655360;   // [2048][128]
  u16* WguT = wb + 917504;   // [2048][128]
  u16* WodT = wb + 1179648;  // [128][2048]
  u16* WouT = wb + 1441792;  // [2048][128]
  u16* cqw  = wb + 1703936;
  u16* ckw  = wb + 1704064;
  u16* csink= wb + 1704192;

  // byte offsets
  const size_t O_QLAT = 4198400;    // [4096][128] bf16 (olat lives here later)
  const size_t O_GLAT = 5246976;    // [4096][128] bf16 (dead after k_mid_all -> rz scratch)
  const size_t O_QRAW = 6295552;    // [4096][2048] bf16 (RAW q; norm fused in attn)
  const size_t O_GRAW = 23072768;   // [4096][2048] bf16 (attn writes out in-place)
  const size_t O_KRAW = 39849984;   // [32768][128] bf16 (dead after k_mid_all -> psum f32 x4)
  const size_t O_VRAW = 48238592;   // [32768][128] bf16
  const size_t O_KT   = 56627200;   // [32][1024][128] bf16
  const size_t O_VTT  = 65015808;   // [32][128][1024] f16
  const size_t O_QTAB = 73404416;   // [2048][64] float2 (1 MB)
  const size_t O_KTAB = 74452992;   // [1024][64] float2 (512 KB)
  const size_t O_NMAX = 74977280;   // [256] int

  const int* spos = (const int*)d_in[2];
  const int* tok  = (const int*)d_in[3];

  k_detect<<<1, 64, 0, stream>>>((const u32*)d_in[0], flag);

  WtArgs wa;
  wa.s[0] = d_in[4];  wa.s[1] = d_in[6];  wa.s[2] = d_in[10]; wa.s[3] = d_in[11];
  wa.s[4] = d_in[5];  wa.s[5] = d_in[7];  wa.s[6] = d_in[8];  wa.s[7] = d_in[9];
  wa.vq = d_in[12]; wa.vk = d_in[13]; wa.vs = d_in[14];
  k_wtab<<<1186, 256, 0, stream>>>(wa, wb, flag, spos, tok,
      (float2*)(ws + O_QTAB), (float2*)(ws + O_KTAB), (int*)(ws + O_NMAX));

  k_down_all<<<2304, 256, 0, stream>>>(d_in[0], d_in[1], BdT, BkvT,
      (u16*)(ws + O_QLAT), (u16*)(ws + O_GLAT), (u16*)(ws + O_KRAW), (u16*)(ws + O_VRAW), flag);

  k_mid_all<<<12800, 256, 0, stream>>>((const u16*)(ws + O_QLAT), (const u16*)(ws + O_GLAT),
      WquT, WguT, (u16*)(ws + O_QRAW), (u16*)(ws + O_GRAW),
      (const u16*)(ws + O_KRAW), (u16*)(ws + O_KT), (const u16*)(ws + O_VRAW), (u16*)(ws + O_VTT),
      ckw, (const float2*)(ws + O_KTAB), flag);

  k_attn<<<8192, 256, 0, stream>>>((const u16*)(ws + O_QRAW), (const u16*)(ws + O_KT),
      (const u16*)(ws + O_VTT), (const u16*)(ws + O_GRAW), spos, tok, csink, cqw,
      (const float2*)(ws + O_QTAB), (const int*)(ws + O_NMAX),
      (float*)(ws + O_GLAT), (u16*)(ws + O_GRAW));

  k_olat_part<<<1024, 256, 0, stream>>>((const u16*)(ws + O_GRAW), WodT, (float*)(ws + O_KRAW));
  k_osum<<<512, 256, 0, stream>>>((const float*)(ws + O_KRAW), (u16*)(ws + O_QLAT));
  k_gemm_up<<<dim3(32,64), 256, 0, stream>>>((const u16*)(ws + O_QLAT), WouT, d_out, 2048, flag, 1);
}

// Round 7
// 503.934 us; speedup vs baseline: 1.2563x; 1.2563x over previous
//
#include <hip/hip_runtime.h>

typedef unsigned short u16;
typedef unsigned int u32;
typedef __attribute__((ext_vector_type(8))) short bf16x8;
typedef __attribute__((ext_vector_type(8))) _Float16 f16x8;
typedef __attribute__((ext_vector_type(4))) float f32x4;

__device__ __forceinline__ float b2f(u16 u) {
  union { u32 i; float f; } v; v.i = ((u32)u) << 16; return v.f;
}
__device__ __forceinline__ u16 f2b(float f) {
  u32 u = __builtin_bit_cast(u32, f);
  u32 r = u + 0x7FFFu + ((u >> 16) & 1u);
  return (u16)(r >> 16);
}
__device__ __forceinline__ u16 f2h(float f) {
  return __builtin_bit_cast(u16, (_Float16)f);
}
__device__ __forceinline__ float h2f(u16 u) {
  return (float)__builtin_bit_cast(_Float16, u);
}
__device__ __forceinline__ float wsum(float v) {
  #pragma unroll
  for (int o = 32; o; o >>= 1) v += __shfl_xor(v, o);
  return v;
}

// ---------- dtype detector: flag=0 bf16 storage, flag=1 fp32 ----------
__global__ void k_detect(const u32* x, int* flag) {
  int lane = threadIdx.x;
  u32 w = x[lane * 131 + 7];
  float v = b2f((u16)(w & 0xFFFF));
  float a = fabsf(v);
  bool sane = (a > 1e-3f) && (a < 100.0f);
  unsigned long long m = __ballot(sane);
  if (lane == 0) flag[0] = (__popcll(m) >= 32) ? 0 : 1;
}

// ---------- weight transposes + vec convert + sincos tables + nmax, ONE launch ----------
// ids 0..415: transposes; 416: vec convert; 417..1184: qtab/ktab sincos; 1185: nmaxg.
struct WtArgs {
  const void* s[8];
  const void* vq; const void* vk; const void* vs;
};
__global__ __launch_bounds__(256)
void k_wtab(WtArgs a, u16* wb, const int* flag, const int* spos, const int* tok,
            float2* qtab, float2* ktab, int* nmaxg) {
  __shared__ u16 Ts[64][66];
  int id = blockIdx.x, t = threadIdx.x;
  if (id >= 417) {
    if (id == 1185) {  // nmaxg[tile]: count of spos[n] < tok0 + tile*16 + 15 (QBLK=16)
      if (t < 128) {
        int lim = tok[0] + t * 16 + 15;
        int lo = 0, hi = 1024;
        #pragma unroll 1
        while (lo < hi) { int mid = (lo + hi) >> 1; if (spos[mid] < lim) lo = mid + 1; else hi = mid; }
        nmaxg[t] = lo;
      }
      return;
    }
    int rid = (id - 417) * 4 + (t >> 6);
    int lane = t & 63;
    float invf = __expf(-(float)lane * (9.210340371976184f / 64.0f));
    if (rid < 2048) {
      float pos = (float)(tok[0] + rid);
      float sn, cs; sincosf(pos * invf, &sn, &cs);
      qtab[rid * 64 + lane] = make_float2(cs, sn);
    } else {
      int n = rid - 2048;
      float pos = (float)spos[n];
      float sn, cs; sincosf(pos * invf, &sn, &cs);
      ktab[n * 64 + lane] = make_float2(cs, sn);
    }
    return;
  }
  int dt = flag[0];
  if (id == 416) {  // vec convert
    u16* dq = wb + 1703936; u16* dk = wb + 1704064; u16* ds = wb + 1704192;
    if (t < 128) dq[t] = dt ? f2b(((const float*)a.vq)[t]) : ((const u16*)a.vq)[t];
    else if (t < 256) dk[t-128] = dt ? f2b(((const float*)a.vk)[t-128]) : ((const u16*)a.vk)[t-128];
    if (t < 16) ds[t] = dt ? f2b(((const float*)a.vs)[t]) : ((const u16*)a.vs)[t];
    return;
  }
  const int cum[9] = {0,64,128,144,160,224,288,352,416};
  const int gsh[8] = {1,1,1,1,5,5,1,5};
  const int Ks[8]  = {2048,2048,512,512,128,128,2048,128};
  const int Ns[8]  = {128,128,128,128,2048,2048,128,2048};
  const unsigned dsts[8] = {0,262144,524288,589824,655360,917504,1179648,1441792};
  int seg = 0;
  #pragma unroll
  for (int i = 0; i < 7; ++i) seg += (id >= cum[i+1]);
  int rel = id - cum[seg];
  int bx = rel & ((1 << gsh[seg]) - 1), by = rel >> gsh[seg];
  int K = Ks[seg], N = Ns[seg];
  const void* src = a.s[seg];
  u16* dst = wb + dsts[seg];
  int col0 = bx * 64, k0 = by * 64;
  int lr = t >> 4, lc = (t & 15) * 4;
  if (dt) {
    #pragma unroll
    for (int p = 0; p < 4; ++p) {
      int kr = lr + p * 16;
      float4 v = *(const float4*)((const float*)src + (size_t)(k0 + kr) * N + col0 + lc);
      Ts[kr][lc+0] = f2b(v.x); Ts[kr][lc+1] = f2b(v.y);
      Ts[kr][lc+2] = f2b(v.z); Ts[kr][lc+3] = f2b(v.w);
    }
  } else {
    #pragma unroll
    for (int p = 0; p < 4; ++p) {
      int kr = lr + p * 16;
      uint2 v = *(const uint2*)((const u16*)src + (size_t)(k0 + kr) * N + col0 + lc);
      *(uint2*)&Ts[kr][lc] = v;
    }
  }
  __syncthreads();
  int col = t >> 2, ks = (t & 3) * 16;
  u16 tmp[16];
  #pragma unroll
  for (int i = 0; i < 16; ++i) tmp[i] = Ts[ks + i][col];
  u16* dp = dst + (size_t)(col0 + col) * K + k0 + ks;
  *(uint4*)dp = *(uint4*)&tmp[0];
  *(uint4*)(dp + 8) = *(uint4*)&tmp[8];
}

// ---------- skinny GEMM body: C = A[M][K]*B, BT[N][K]; M-tile 16, N=JW*64 ----------
template<int JW>
__device__ __forceinline__ void skinny_body(const void* A, const u16* BT, u16* C0, u16* C1,
    int K, bool a32, int m0, int tid, u16 (*As)[40]) {
  int wave = tid >> 6, lane = tid & 63, quad = lane >> 4, l16 = lane & 15;
  f32x4 acc[JW];
  #pragma unroll
  for (int j = 0; j < JW; ++j) acc[j] = (f32x4){0.f,0.f,0.f,0.f};
  int row32 = tid >> 4, kp32 = (tid & 15) * 2;
  int row16 = tid >> 2, kp16 = (tid & 3) * 8;
  float2 pf32 = {};
  uint4 pf16 = {};
  if (a32) pf32 = *(const float2*)((const float*)A + (size_t)(m0+row32)*K + kp32);
  else if (tid < 64) pf16 = *(const uint4*)((const u16*)A + (size_t)(m0+row16)*K + kp16);
  uint4 bf[JW];
  #pragma unroll
  for (int j = 0; j < JW; ++j) {
    int col = wave*(JW*16) + j*16 + l16;
    bf[j] = *(const uint4*)(BT + (size_t)col*K + quad*8);
  }
  for (int k0 = 0; k0 < K; k0 += 32) {
    if (a32) { As[row32][kp32] = f2b(pf32.x); As[row32][kp32+1] = f2b(pf32.y); }
    else if (tid < 64) *(uint4*)&As[row16][kp16] = pf16;
    __syncthreads();
    int k1 = k0 + 32;
    uint4 bn[JW];
    if (k1 < K) {
      if (a32) pf32 = *(const float2*)((const float*)A + (size_t)(m0+row32)*K + k1 + kp32);
      else if (tid < 64) pf16 = *(const uint4*)((const u16*)A + (size_t)(m0+row16)*K + k1 + kp16);
      #pragma unroll
      for (int j = 0; j < JW; ++j) {
        int col = wave*(JW*16) + j*16 + l16;
        bn[j] = *(const uint4*)(BT + (size_t)col*K + k1 + quad*8);
      }
    }
    bf16x8 af = *(const bf16x8*)&As[l16][quad*8];
    #pragma unroll
    for (int j = 0; j < JW; ++j)
      acc[j] = __builtin_amdgcn_mfma_f32_16x16x32_bf16(af, __builtin_bit_cast(bf16x8, bf[j]), acc[j], 0, 0, 0);
    __syncthreads();
    #pragma unroll
    for (int j = 0; j < JW; ++j) bf[j] = bn[j];
  }
  #pragma unroll
  for (int j = 0; j < JW; ++j) {
    int col = wave*(JW*16) + j*16 + l16;
    u16* Cp = (col < 128) ? C0 : C1;
    int cc = col & 127;
    #pragma unroll
    for (int r = 0; r < 4; ++r)
      Cp[(size_t)(m0 + quad*4 + r)*128 + cc] = f2b(acc[j][r]);
  }
}

// ---------- up GEMM body: C[M][N] = A[M][128]*B, BT[N][128]; 64x64 tile ----------
__device__ __forceinline__ void gemm_up_body(const u16* A, const u16* BT, void* C, int ldc,
    bool o32, int m0, int n0, int tid, u16 (*As)[40]) {
  int wave = tid >> 6, lane = tid & 63, quad = lane >> 4, l16 = lane & 15;
  f32x4 acc[4] = {};
  int row = tid >> 2, kp = (tid & 3) * 8;
  uint4 pa = *(const uint4*)(A + (size_t)(m0+row)*128 + kp);
  uint4 bf[4];
  #pragma unroll
  for (int j = 0; j < 4; ++j)
    bf[j] = *(const uint4*)(BT + (size_t)(n0 + j*16 + l16)*128 + quad*8);
  #pragma unroll
  for (int k0 = 0; k0 < 128; k0 += 32) {
    *(uint4*)&As[row][kp] = pa;
    __syncthreads();
    uint4 bn[4];
    if (k0 < 96) {
      pa = *(const uint4*)(A + (size_t)(m0+row)*128 + k0 + 32 + kp);
      #pragma unroll
      for (int j = 0; j < 4; ++j)
        bn[j] = *(const uint4*)(BT + (size_t)(n0 + j*16 + l16)*128 + k0 + 32 + quad*8);
    }
    bf16x8 af = *(const bf16x8*)&As[wave*16 + l16][quad*8];
    #pragma unroll
    for (int j = 0; j < 4; ++j)
      acc[j] = __builtin_amdgcn_mfma_f32_16x16x32_bf16(af, __builtin_bit_cast(bf16x8, bf[j]), acc[j], 0, 0, 0);
    __syncthreads();
    #pragma unroll
    for (int j = 0; j < 4; ++j) bf[j] = bn[j];
  }
  #pragma unroll
  for (int j = 0; j < 4; ++j) {
    #pragma unroll
    for (int r = 0; r < 4; ++r) {
      size_t ci = (size_t)(m0 + wave*16 + quad*4 + r)*ldc + n0 + j*16 + l16;
      float v = acc[j][r];
      if (o32) ((float*)C)[ci] = v; else ((u16*)C)[ci] = f2b(v);
    }
  }
}

// ---------- k post body: RMSNorm+RoPE (sincos from ktab); -> kT ----------
__device__ __forceinline__ void kpost_body(const u16* kraw, u16* kT, const u16* kw,
                                           const float2* ktab, int rel, int tid) {
  int wave = tid >> 6, lane = tid & 63;
  int rr = rel * 4 + wave;               // (b*1024+n)*16 + h
  int n = (rr >> 4) & 1023, b = rr >> 14, h = rr & 15;
  size_t base = (size_t)rr * 128;
  float x0 = b2f(kraw[base + lane]);
  float x1 = b2f(kraw[base + lane + 64]);
  float ss = wsum(x0*x0 + x1*x1);
  float inv = rsqrtf(ss * (1.0f/128.0f) + 1e-6f);
  float y0 = x0 * inv * b2f(kw[lane]);
  float y1 = x1 * inv * b2f(kw[lane + 64]);
  float2 cs2 = ktab[n * 64 + lane];
  size_t ob = ((size_t)(b*16 + h) * 1024 + n) * 128;
  kT[ob + lane]      = f2b(y0*cs2.x - y1*cs2.y);
  kT[ob + lane + 64] = f2b(y1*cs2.x + y0*cs2.y);
}

// ---------- V transpose body: vraw -> vtt[b,h,dh,n] (f16) ----------
__device__ __forceinline__ void vtrans_body(const u16* vraw, u16* vtt, int bid, int t,
                                            u16 (*Vs)[136]) {
  int ng = bid & 15, bh = bid >> 4;
  int b = bh >> 4, h = bh & 15;
  int n0 = ng * 64;
  int li = t >> 4, seg = (t & 15) * 8;
  #pragma unroll
  for (int p = 0; p < 4; ++p) {
    int i = li + p * 16;
    size_t row = (size_t)(b*1024 + n0 + i) * 16 + h;
    *(uint4*)&Vs[i][seg] = *(const uint4*)(vraw + row*128 + seg);
  }
  __syncthreads();
  int dh = t >> 1, nh = (t & 1) * 32;
  u16 outv[32];
  #pragma unroll
  for (int i = 0; i < 32; ++i) outv[i] = f2h(b2f(Vs[nh + i][dh]));
  u16* dst = vtt + ((size_t)bh * 128 + dh) * 1024 + n0 + nh;
  *(uint4*)(dst)      = *(uint4*)&outv[0];
  *(uint4*)(dst + 8)  = *(uint4*)&outv[8];
  *(uint4*)(dst + 16) = *(uint4*)&outv[16];
  *(uint4*)(dst + 24) = *(uint4*)&outv[24];
}

// ---------- merged launches ----------
__global__ __launch_bounds__(256)
void k_down_all(const void* x, const void* snap, const u16* BdT, const u16* BkvT,
                u16* qlat, u16* glat, u16* kraw, u16* vraw, const int* flag) {
  __shared__ u16 As[16][40];
  int id = blockIdx.x;
  bool a32 = flag[0] != 0;
  if (id < 256) skinny_body<4>(x, BdT, qlat, glat, 2048, a32, id*16, threadIdx.x, As);
  else          skinny_body<4>(snap, BkvT, kraw, vraw, 512, a32, (id-256)*16, threadIdx.x, As);
}

__global__ __launch_bounds__(256)
void k_mid_all(const u16* qlat, const u16* glat, const u16* WquT, const u16* WguT,
               u16* qraw, u16* graw, const u16* kraw, u16* kT, const u16* vraw, u16* vtt,
               const u16* ckw, const float2* ktab, const int* flag) {
  __shared__ u16 smem[64*136];
  int id = blockIdx.x, tid = threadIdx.x;
  if (id < 4096) {
    u16 (*As)[40] = (u16 (*)[40])smem;
    int rel = id & 2047;
    const u16* A  = (id < 2048) ? qlat : glat;
    const u16* BT = (id < 2048) ? WquT : WguT;
    u16* C        = (id < 2048) ? qraw : graw;
    gemm_up_body(A, BT, C, 2048, false, (rel >> 5) * 64, (rel & 31) * 64, tid, As);
  } else if (id < 12288) {
    kpost_body(kraw, kT, ckw, ktab, id - 4096, tid);
  } else {
    vtrans_body(vraw, vtt, id - 12288, tid, (u16 (*)[136])smem);
  }
}

// ---------- k_olat K-split: 1024 blocks (256 m-tiles x 4 K-slices) -> f32 partials ----------
__global__ __launch_bounds__(256)
void k_olat_part(const u16* Ao, const u16* BT, float* P) {
  __shared__ u16 As[16][40];
  int bid = blockIdx.x;
  int ks = bid & 3, m0 = (bid >> 2) * 16;
  int kbase = ks * 512;
  int tid = threadIdx.x;
  int wave = tid >> 6, lane = tid & 63, quad = lane >> 4, l16 = lane & 15;
  f32x4 acc[2] = {};
  int row16 = tid >> 2, kp16 = (tid & 3) * 8;
  uint4 pf16 = {};
  if (tid < 64) pf16 = *(const uint4*)(Ao + (size_t)(m0+row16)*2048 + kbase + kp16);
  uint4 bf[2];
  #pragma unroll
  for (int j = 0; j < 2; ++j) {
    int col = wave*32 + j*16 + l16;
    bf[j] = *(const uint4*)(BT + (size_t)col*2048 + kbase + quad*8);
  }
  for (int k0 = 0; k0 < 512; k0 += 32) {
    if (tid < 64) *(uint4*)&As[row16][kp16] = pf16;
    __syncthreads();
    int k1 = k0 + 32;
    uint4 bn[2];
    if (k1 < 512) {
      if (tid < 64) pf16 = *(const uint4*)(Ao + (size_t)(m0+row16)*2048 + kbase + k1 + kp16);
      #pragma unroll
      for (int j = 0; j < 2; ++j) {
        int col = wave*32 + j*16 + l16;
        bn[j] = *(const uint4*)(BT + (size_t)col*2048 + kbase + k1 + quad*8);
      }
    }
    bf16x8 afr = *(const bf16x8*)&As[l16][quad*8];
    #pragma unroll
    for (int j = 0; j < 2; ++j)
      acc[j] = __builtin_amdgcn_mfma_f32_16x16x32_bf16(afr, __builtin_bit_cast(bf16x8, bf[j]), acc[j], 0, 0, 0);
    __syncthreads();
    #pragma unroll
    for (int j = 0; j < 2; ++j) bf[j] = bn[j];
  }
  #pragma unroll
  for (int j = 0; j < 2; ++j) {
    int col = wave*32 + j*16 + l16;
    #pragma unroll
    for (int r = 0; r < 4; ++r)
      P[((size_t)ks*4096 + m0 + quad*4 + r)*128 + col] = acc[j][r];
  }
}

// ---------- k_osum: sum 4 f32 partial slabs -> olat bf16 ----------
__global__ __launch_bounds__(256)
void k_osum(const float* P, u16* olat) {
  int idx = (blockIdx.x * 256 + threadIdx.x) * 4;
  float4 a = *(const float4*)(P + idx);
  float4 b = *(const float4*)(P + 524288 + idx);
  float4 c = *(const float4*)(P + 1048576 + idx);
  float4 d = *(const float4*)(P + 1572864 + idx);
  u16 o4[4];
  o4[0] = f2b(((a.x + b.x) + c.x) + d.x);
  o4[1] = f2b(((a.y + b.y) + c.y) + d.y);
  o4[2] = f2b(((a.z + b.z) + c.z) + d.z);
  o4[3] = f2b(((a.w + b.w) + c.w) + d.w);
  *(uint2*)(olat + idx) = *(uint2*)&o4[0];
}

__global__ __launch_bounds__(256)
void k_gemm_up(const u16* A, const u16* BT, void* C, int ldc, const int* flag, int out_dyn) {
  __shared__ u16 As[64][40];
  gemm_up_body(A, BT, C, ldc, out_dyn && flag[0], blockIdx.y*64, blockIdx.x*64, threadIdx.x, As);
}

// ---------- attention phase 2 (EXACT v6 body): top-64 + softmax, lockstep-2 x 2 halves ----------
// Lockstep-2 fits the 48-VGPR allocation (lockstep-4 spilled: v5; 8-wave bounds spilled: v7).
// Numerics bit-identical to v1.
template<int NJ>
__device__ __forceinline__ void attn_phase2(char* scB, float* rzb, int tl0, int lane,
                                            int nmax, float sinkv, bool do_search) {
  int c0 = lane * 8;
  #pragma unroll 1
  for (int half = 0; half < 2; ++half) {
    float sv[2][NJ]; int key[2][NJ];
    #pragma unroll
    for (int s2 = 0; s2 < 2; ++s2) {
      int tl = tl0 + half*2 + s2;
      int sxor = (tl & 7) << 4;
      const char* rowp = scB + tl*2048;
      uint4 r0 = *(const uint4*)(rowp + ((lane*16) ^ sxor));
      #pragma unroll
      for (int j = 0; j < 8; ++j)
        sv[s2][j] = (c0 + j < nmax) ? h2f(((const u16*)&r0)[j]) : -INFINITY;
      if constexpr (NJ == 16) {
        uint4 r1 = *(const uint4*)(rowp + (1024 + ((lane*16) ^ sxor)));
        #pragma unroll
        for (int j = 0; j < 8; ++j)
          sv[s2][j+8] = (c0 + j + 512 < nmax) ? h2f(((const u16*)&r1)[j]) : -INFINITY;
      }
    }
    // local max + v1-exact key grid: key = (int)clamp(f*256+2048, 0, 4095)
    float mx[2];
    #pragma unroll
    for (int s2 = 0; s2 < 2; ++s2) {
      float m = -INFINITY;
      #pragma unroll
      for (int j = 0; j < NJ; ++j) {
        float f = sv[s2][j];
        m = fmaxf(m, f);
        float fs = fminf(fmaxf(f * 256.0f + 2048.0f, 0.0f), 4095.0f);
        key[s2][j] = (int)fs;
      }
      mx[s2] = m;
    }
    #pragma unroll
    for (int os = 32; os; os >>= 1) {
      mx[0] = fmaxf(mx[0], __shfl_xor(mx[0], os));
      mx[1] = fmaxf(mx[1], __shfl_xor(mx[1], os));
    }
    // 12-iter integer binary search, 2 rows lockstep (identical result to v1)
    int lo2[2] = {0, 0};
    if (do_search) {
      int hi2[2] = {4096, 4096};
      #pragma unroll 1
      for (int it = 0; it < 12; ++it) {
        #pragma unroll
        for (int s2 = 0; s2 < 2; ++s2) {
          int mid = (lo2[s2] + hi2[s2]) >> 1;
          int c = 0;
          #pragma unroll
          for (int j = 0; j < NJ; ++j) c += (int)__popcll(__ballot(key[s2][j] >= mid));
          if (c >= 64) lo2[s2] = mid; else hi2[s2] = mid;
        }
      }
    }
    // exp + interleaved sum butterfly; store UNSCALED f16 weights (v1-exact)
    float m2[2], zp[2];
    u16 wq[2][16];
    #pragma unroll
    for (int s2 = 0; s2 < 2; ++s2) {
      m2[s2] = fmaxf(mx[s2], sinkv);
      float z = 0.f;
      #pragma unroll
      for (int j = 0; j < NJ; ++j) {
        float e = (key[s2][j] >= lo2[s2] && sv[s2][j] > -1e37f) ? __expf(sv[s2][j] - m2[s2]) : 0.f;
        z += e;
        wq[s2][j] = f2h(e);
      }
      zp[s2] = z;
    }
    #pragma unroll
    for (int os = 32; os; os >>= 1) {
      zp[0] += __shfl_xor(zp[0], os);
      zp[1] += __shfl_xor(zp[1], os);
    }
    #pragma unroll
    for (int s2 = 0; s2 < 2; ++s2) {
      int tl = tl0 + half*2 + s2;
      float Z = zp[s2] + __expf(sinkv - m2[s2]);
      if (lane == 0) rzb[tl] = 1.0f / Z;
      int sxor = (tl & 7) << 4;
      char* rowp = scB + tl*2048;
      *(uint4*)(rowp + ((lane*16) ^ sxor)) = *(uint4*)&wq[s2][0];
      if constexpr (NJ == 16)
        *(uint4*)(rowp + (1024 + ((lane*16) ^ sxor))) = *(uint4*)&wq[s2][8];
    }
  }
}

// ---------- fused attention v8 = v6 (proven 183 us): QBLK=16, 5 blocks/CU ----------
// v7's QBLK=8 + 8-block bid spilled (VGPR cap 64 < ~90 live -> 245 MB scratch WRITE).
// Stable point: LDS 32 KB (5 blocks/CU), 48 VGPR, lockstep-2 phase 2.
__global__ __launch_bounds__(256, 5)
void k_attn(const u16* qraw, const u16* kT, const u16* vtt, const u16* graw,
            const int* spos, const int* tok, const u16* sink, const u16* qw,
            const float2* qtab, const int* nmaxg, float* rzg, u16* o) {
  __shared__ u16 sc[16*1024];        // scores/weights (f16), swizzled rows, 2048B stride
  char* scB = (char*)sc;
  u16 (*Qs)[136] = (u16 (*)[136])sc;  // transient overlay (consumed before sc writes)

  int tid = threadIdx.x;
  int wave = tid >> 6, lane = tid & 63, quad = lane >> 4, l16 = lane & 15;
  int bid0 = blockIdx.x;
  int bid = (bid0 & 7) * 512 + (bid0 >> 3);   // XCD k -> contiguous work chunk (4 bh slices)
  int tile = bid & 127, bh = bid >> 7;
  int h = bh & 15, b = bh >> 4;
  int t0 = tile * 16;
  int tok0 = tok[0];
  float* rzb = rzg + bid * 16;

  // fused q RMSNorm + RoPE into Qs (values identical to v1; sincos from table)
  {
    float qw0 = b2f(qw[lane]), qw1 = b2f(qw[lane + 64]);
    #pragma unroll 1
    for (int s = 0; s < 4; ++s) {
      int i = wave*4 + s;
      size_t base = ((size_t)(b*2048 + t0 + i))*2048 + h*128;
      float x0 = b2f(qraw[base + lane]);
      float x1 = b2f(qraw[base + lane + 64]);
      float ss = wsum(x0*x0 + x1*x1);
      float inv = rsqrtf(ss * (1.0f/128.0f) + 1e-6f);
      float y0 = x0 * inv * qw0;
      float y1 = x1 * inv * qw1;
      float2 cs2 = qtab[(size_t)(t0 + i)*64 + lane];
      Qs[i][lane]      = f2b(y0*cs2.x - y1*cs2.y);
      Qs[i][lane + 64] = f2b(y1*cs2.x + y0*cs2.y);
    }
  }
  __syncthreads();

  int nmax = nmaxg[tile];
  int pmax = (nmax + 63) >> 6;
  int kkmax = (nmax + 31) >> 5;

  bf16x8 af[4];
  #pragma unroll
  for (int ks = 0; ks < 4; ++ks) af[ks] = *(const bf16x8*)&Qs[l16][ks*32 + quad*8];
  __syncthreads();   // protect Qs before sc writes

  // phase 1: scores for p < pmax into swizzled sc; cols >= nmax left as garbage
  // (masked by col<nmax select in phase 2; cols in [nmax, pmax*64) get -inf via pn)
  const u16* kTb = kT + (size_t)bh * 131072;
  int nrow = wave*16 + l16;
  uint4 kf[4];
  int pn = 0;
  if (pmax > 0) {
    const u16* kr = kTb + (size_t)nrow * 128 + quad*8;
    #pragma unroll
    for (int ks = 0; ks < 4; ++ks) kf[ks] = *(const uint4*)(kr + ks*32);
    pn = spos[nrow];
  }
  int lim0 = tok0 + t0;
  #pragma unroll 1
  for (int p = 0; p < pmax; ++p) {
    uint4 kn[4];
    int pn_next = 0;
    if (p + 1 < pmax) {
      const u16* kr = kTb + (size_t)((p+1)*64 + nrow) * 128 + quad*8;
      #pragma unroll
      for (int ks = 0; ks < 4; ++ks) kn[ks] = *(const uint4*)(kr + ks*32);
      pn_next = spos[(p+1)*64 + nrow];
    }
    f32x4 c = {};
    __builtin_amdgcn_s_setprio(1);
    #pragma unroll
    for (int ks = 0; ks < 4; ++ks)
      c = __builtin_amdgcn_mfma_f32_16x16x32_bf16(af[ks], __builtin_bit_cast(bf16x8, kf[ks]), c, 0, 0, 0);
    __builtin_amdgcn_s_setprio(0);
    int n = p*64 + nrow;
    #pragma unroll
    for (int r = 0; r < 4; ++r) {
      int t = quad*4 + r;
      float s = c[r] * 0.08838834764831845f;
      if (pn >= lim0 + t) s = -INFINITY;
      *(u16*)(scB + ((t*2048 + n*2) ^ ((t&7)<<4))) = f2h(s);
    }
    #pragma unroll
    for (int ks = 0; ks < 4; ++ks) kf[ks] = kn[ks];
    pn = pn_next;
  }
  __syncthreads();

  float sinkv = b2f(sink[h]);

  // phase 2 (numerics == v1); work proportional to nmax; lockstep-2 (fits 48 VGPR)
  int tl0 = wave*4;
  bool do_search = (nmax > 64);
  if (nmax > 512) attn_phase2<16>(scB, rzb, tl0, lane, nmax, sinkv, do_search);
  else            attn_phase2<8> (scB, rzb, tl0, lane, nmax, sinkv, do_search);
  __syncthreads();

  // prefetch rz + gate values for the epilogue (hidden under PV MFMA)
  int dh0 = wave * 32;
  float rz4[4];
  u16 g0r[4], g1r[4];
  #pragma unroll
  for (int r = 0; r < 4; ++r) {
    int t = quad*4 + r;
    rz4[r] = rzb[t];
    size_t oi = ((size_t)(b*2048 + t0 + t))*2048 + h*128 + dh0 + l16;
    g0r[r] = graw[oi];
    g1r[r] = graw[oi + 16];
  }

  // phase 3: dense PV via MFMA f16 over kk < kkmax (weights exactly 0 beyond nmax)
  const u16* vbase = vtt + (size_t)bh * 131072;
  const u16* vr0 = vbase + (size_t)(dh0 + l16)*1024 + quad*8;
  const u16* vr1 = vbase + (size_t)(dh0 + 16 + l16)*1024 + quad*8;
  f32x4 acc0 = {}, acc1 = {};
  uint4 vf0 = *(const uint4*)vr0;
  uint4 vf1 = *(const uint4*)vr1;
  int axor = (l16&7) << 4;
  const char* arow = scB + l16*2048;
  #pragma unroll 1
  for (int kk = 0; kk < kkmax; ++kk) {
    uint4 vn0, vn1;
    if (kk + 1 < kkmax) {
      vn0 = *(const uint4*)(vr0 + (kk+1)*32);
      vn1 = *(const uint4*)(vr1 + (kk+1)*32);
    }
    f16x8 a = *(const f16x8*)(arow + ((kk*64 + quad*16) ^ axor));
    __builtin_amdgcn_s_setprio(1);
    acc0 = __builtin_amdgcn_mfma_f32_16x16x32_f16(a, __builtin_bit_cast(f16x8, vf0), acc0, 0, 0, 0);
    acc1 = __builtin_amdgcn_mfma_f32_16x16x32_f16(a, __builtin_bit_cast(f16x8, vf1), acc1, 0, 0, 0);
    __builtin_amdgcn_s_setprio(0);
    vf0 = vn0; vf1 = vn1;
  }

  // epilogue: *1/Z, *sigmoid(gate), store (o aliases graw; same-thread RaW only)
  #pragma unroll
  for (int r = 0; r < 4; ++r) {
    int t = quad*4 + r;
    size_t oi = ((size_t)(b*2048 + t0 + t))*2048 + h*128 + dh0 + l16;
    float g0 = 1.0f / (1.0f + __expf(-b2f(g0r[r])));
    float g1 = 1.0f / (1.0f + __expf(-b2f(g1r[r])));
    o[oi] = f2b(acc0[r] * rz4[r] * g0);
    o[oi + 16] = f2b(acc1[r] * rz4[r] * g1);
  }
}

extern "C" void kernel_launch(void* const* d_in, const int* in_sizes, int n_in,
                              void* d_out, int out_size, void* d_ws, size_t ws_size,
                              hipStream_t stream) {
  char* ws = (char*)d_ws;
  int* flag = (int*)(ws + 0);
  u16* wb = (u16*)(ws + 4096);

  // wb element offsets
  u16* BdT  = wb + 0;        // [256][2048]
  u16* BkvT = wb + 524288;   // [256][512]
  u16* WquT = wb + 655360;   // [2048][128]
  u16* WguT = wb + 917504;   // [2048][128]
  u16* WodT = wb + 1179648;  // [128][2048]
  u16* WouT = wb + 1441792;  // [2048][128]
  u16* cqw  = wb + 1703936;
  u16* ckw  = wb + 1704064;
  u16* csink= wb + 1704192;

  // byte offsets
  const size_t O_QLAT = 4198400;    // [4096][128] bf16 (olat lives here later)
  const size_t O_GLAT = 5246976;    // [4096][128] bf16 (dead after k_mid_all -> rz scratch)
  const size_t O_QRAW = 6295552;    // [4096][2048] bf16 (RAW q; norm fused in attn)
  const size_t O_GRAW = 23072768;   // [4096][2048] bf16 (attn writes out in-place)
  const size_t O_KRAW = 39849984;   // [32768][128] bf16 (dead after k_mid_all -> psum f32 x4)
  const size_t O_VRAW = 48238592;   // [32768][128] bf16
  const size_t O_KT   = 56627200;   // [32][1024][128] bf16
  const size_t O_VTT  = 65015808;   // [32][128][1024] f16
  const size_t O_QTAB = 73404416;   // [2048][64] float2 (1 MB)
  const size_t O_KTAB = 74452992;   // [1024][64] float2 (512 KB)
  const size_t O_NMAX = 74977280;   // [128] int

  const int* spos = (const int*)d_in[2];
  const int* tok  = (const int*)d_in[3];

  k_detect<<<1, 64, 0, stream>>>((const u32*)d_in[0], flag);

  WtArgs wa;
  wa.s[0] = d_in[4];  wa.s[1] = d_in[6];  wa.s[2] = d_in[10]; wa.s[3] = d_in[11];
  wa.s[4] = d_in[5];  wa.s[5] = d_in[7];  wa.s[6] = d_in[8];  wa.s[7] = d_in[9];
  wa.vq = d_in[12]; wa.vk = d_in[13]; wa.vs = d_in[14];
  k_wtab<<<1186, 256, 0, stream>>>(wa, wb, flag, spos, tok,
      (float2*)(ws + O_QTAB), (float2*)(ws + O_KTAB), (int*)(ws + O_NMAX));

  k_down_all<<<2304, 256, 0, stream>>>(d_in[0], d_in[1], BdT, BkvT,
      (u16*)(ws + O_QLAT), (u16*)(ws + O_GLAT), (u16*)(ws + O_KRAW), (u16*)(ws + O_VRAW), flag);

  k_mid_all<<<12800, 256, 0, stream>>>((const u16*)(ws + O_QLAT), (const u16*)(ws + O_GLAT),
      WquT, WguT, (u16*)(ws + O_QRAW), (u16*)(ws + O_GRAW),
      (const u16*)(ws + O_KRAW), (u16*)(ws + O_KT), (const u16*)(ws + O_VRAW), (u16*)(ws + O_VTT),
      ckw, (const float2*)(ws + O_KTAB), flag);

  k_attn<<<4096, 256, 0, stream>>>((const u16*)(ws + O_QRAW), (const u16*)(ws + O_KT),
      (const u16*)(ws + O_VTT), (const u16*)(ws + O_GRAW), spos, tok, csink, cqw,
      (const float2*)(ws + O_QTAB), (const int*)(ws + O_NMAX),
      (float*)(ws + O_GLAT), (u16*)(ws + O_GRAW));

  k_olat_part<<<1024, 256, 0, stream>>>((const u16*)(ws + O_GRAW), WodT, (float*)(ws + O_KRAW));
  k_osum<<<512, 256, 0, stream>>>((const float*)(ws + O_KRAW), (u16*)(ws + O_QLAT));
  k_gemm_up<<<dim3(32,64), 256, 0, stream>>>((const u16*)(ws + O_QLAT), WouT, d_out, 2048, flag, 1);
}